// Round 4
// baseline (266.304 us; speedup 1.0000x reference)
//
#include <hip/hip_runtime.h>
#include <hip/hip_bf16.h>

// Problem constants
#define D_MODEL 768
#define NH 12
#define HD 64
#define BATCH 4
#define SEQ 2048
#define BHN (BATCH*NH)        // 48
#define MROWS (BATCH*SEQ)     // 8192

typedef unsigned short u16;
typedef __attribute__((ext_vector_type(8))) short short8;
typedef __attribute__((ext_vector_type(4))) float f32x4;

__device__ inline u16 f2bf(float f){
  union { __hip_bfloat16 h; u16 u; } cv; cv.h = __float2bfloat16(f); return cv.u;
}

// async global->LDS, 16B per lane. LDS dest = wave-uniform base + lane*16.
__device__ inline void async_copy16(const void* g, void* l){
  __builtin_amdgcn_global_load_lds(
      (const __attribute__((address_space(1))) void*)g,
      (__attribute__((address_space(3))) void*)l, 16, 0, 0);
}

// ---------------- cast fp32 -> bf16, vectorized x4 ----------------
__global__ void cast4_kernel(const float* __restrict__ in, u16* __restrict__ out, int n4){
  int i = blockIdx.x*blockDim.x + threadIdx.x;
  if (i < n4){
    const float4 v = ((const float4*)in)[i];
    ushort4 o;
    o.x = f2bf(v.x); o.y = f2bf(v.y); o.z = f2bf(v.z); o.w = f2bf(v.w);
    ((ushort4*)out)[i] = o;
  }
}

// ---------------- transpose + cast: W[K][N] fp32 -> Wt[N][K] bf16 ----------------
__global__ void transpose_cast_kernel(const float* __restrict__ w, u16* __restrict__ wt,
                                      int K, int N){
  __shared__ u16 tile[64][65];
  int k0 = blockIdx.x*64, n0 = blockIdx.y*64;
  int c = threadIdx.x & 63, r0 = threadIdx.x >> 6;
  #pragma unroll
  for (int r = r0; r < 64; r += 4)
    tile[c][r] = f2bf(w[(size_t)(k0+r)*N + n0 + c]);
  __syncthreads();
  #pragma unroll
  for (int r = r0; r < 64; r += 4)
    wt[(size_t)(n0+r)*K + k0 + c] = tile[r][c];
}

// ---------------- bf16 GEMM: C[M,N] = A[M,K] @ Bt[N,K]^T ----------------
// 128x128 tile, BK=32, double-buffered LDS, 2-phase prefetch.
template<int EPI>
__launch_bounds__(256)
__global__ void gemm_bf16(const u16* __restrict__ A, const u16* __restrict__ Bt,
                          const float* __restrict__ bias, float* __restrict__ outf,
                          u16* __restrict__ oq, u16* __restrict__ ok, u16* __restrict__ ovt,
                          int M, int N, int K)
{
  __shared__ alignas(16) char smem[32768];   // As0,As1,Bs0,Bs1: 8KB each
  const int tid = threadIdx.x, wave = tid>>6, lane = tid&63;
  const int lr = lane&15, lg = lane>>4;
  const int m0 = blockIdx.x*128, n0 = blockIdx.y*128;
  const int wr = (wave>>1)*64, wc = (wave&1)*64;
  f32x4 acc[4][4] = {};
  const int srow = wave*32 + (lane>>2);   // staging row (+i*16)
  const int schk = lane&3;                // 16B chunk within 64B row

  auto stage = [&](int kt, int buf){
    char* Ab = smem + buf*8192;
    char* Bb = smem + 16384 + buf*8192;
    #pragma unroll
    for (int i = 0; i < 2; i++){
      int r = srow + i*16;
      async_copy16(A  + (size_t)(m0 + r)*K + kt + schk*8, Ab + (wave*32 + i*16)*64);
      async_copy16(Bt + (size_t)(n0 + r)*K + kt + schk*8, Bb + (wave*32 + i*16)*64);
    }
  };

  const int NT = K >> 5;
  stage(0, 0);
  for (int t = 0; t < NT; t++){
    const int c = t & 1;
    asm volatile("s_waitcnt vmcnt(0)" ::: "memory");
    __builtin_amdgcn_s_barrier();
    if (t+1 < NT) stage((t+1)<<5, c^1);

    const char* Ac = smem + c*8192;
    const char* Bc = smem + 16384 + c*8192;
    short8 a[4], b[4];
    #pragma unroll
    for (int mi = 0; mi < 4; mi++)
      a[mi] = *(const short8*)(Ac + (wr + mi*16 + lr)*64 + lg*16);
    #pragma unroll
    for (int ni = 0; ni < 4; ni++)
      b[ni] = *(const short8*)(Bc + (wc + ni*16 + lr)*64 + lg*16);
    #pragma unroll
    for (int mi = 0; mi < 4; mi++)
      #pragma unroll
      for (int ni = 0; ni < 4; ni++)
        acc[mi][ni] = __builtin_amdgcn_mfma_f32_16x16x32_bf16(a[mi], b[ni], acc[mi][ni], 0, 0, 0);
  }

  // epilogue: C row = (lane>>4)*4 + j, col = lane&15  [verified C/D layout]
  #pragma unroll
  for (int mi = 0; mi < 4; mi++)
  #pragma unroll
  for (int ni = 0; ni < 4; ni++)
  #pragma unroll
  for (int j = 0; j < 4; j++){
    int m = m0 + wr + mi*16 + lg*4 + j;
    int n = n0 + wc + ni*16 + lr;
    float v = acc[mi][ni][j] + bias[n];
    if (EPI == 0){
      outf[(size_t)m*N + n] = v;
    } else {
      int b_ = m >> 11, s = m & 2047;
      int t  = (n >= 1536) ? 2 : (n >= 768 ? 1 : 0);
      int hn = n - t*768;
      int h = hn >> 6, d = hn & 63;
      u16 bf = f2bf(v);
      size_t base = (size_t)(b_*NH + h);
      if (t == 0)      oq [(base*SEQ + s)*HD + d] = bf;
      else if (t == 1) ok [(base*SEQ + s)*HD + d] = bf;
      else             ovt[(base*HD + d)*SEQ + s] = bf;   // V stored transposed
    }
  }
}

// ---------------- flash attention: barrier-free, per-wave independent ----------------
// 768 blocks x 256 threads = 3072 waves (12/CU). Each wave owns 16 q-rows;
// tile pair (p, 127-p) -> uniform 33 KV64-steps per wave. K/V global->VGPR
// (per-XCD L2-resident). No block sync at all; latency hidden by 3 waves/SIMD.
// P bounces through wave-local LDS (2KB each).
__launch_bounds__(256, 3)
__global__ void attn_kernel(const u16* __restrict__ q, const u16* __restrict__ k,
                            const u16* __restrict__ vt, u16* __restrict__ aout)
{
  __shared__ alignas(16) char Ps_all[8192];   // 4 waves x 2KB
  const int b1 = blockIdx.x;                 // 0..767
  const int xcd = b1 & 7, grp = b1 >> 3;     // grp 0..95
  const int bh = xcd*6 + (grp >> 4);         // 6 heads per XCD
  const int pairblk = grp & 15;              // 0..15
  const int tid = threadIdx.x, wave = tid>>6, lane = tid&63;
  const int pr = pairblk*4 + wave;           // pair index 0..63
  const int lr = lane&15, lg = lane>>4;
  char* Ps = Ps_all + wave*2048;
  const int b_ = bh / NH, h = bh % NH;
  const u16* qp = q  + (size_t)bh*SEQ*HD;
  const u16* kp = k  + (size_t)bh*SEQ*HD;
  const u16* vp = vt + (size_t)bh*HD*SEQ;
  const float SC = 0.125f * 1.44269504f;     // scale * log2(e), use exp2

  #pragma unroll 1
  for (int half = 0; half < 2; half++){
    const int t = half ? (127 - pr) : pr;    // 16-row tile index 0..127
    const int q0 = t*16;
    const int nkv = (t >> 2) + 1;            // KV64 steps

    // Q fragments (A-frag: m=lr, k = ks*32+lg*8)
    short8 aq[2];
    #pragma unroll
    for (int ks = 0; ks < 2; ks++)
      aq[ks] = *(const short8*)(qp + (size_t)(q0 + lr)*HD + ks*32 + lg*8);

    float mrow[4], lsum[4];
    f32x4 o[4] = {};
    #pragma unroll
    for (int jj = 0; jj < 4; jj++){ mrow[jj] = -INFINITY; lsum[jj] = 0.f; }

    #pragma unroll 1
    for (int kvb = 0; kvb < nkv; kvb++){
      const int kv0 = kvb*64;

      // K tile -> regs (B-frag: n=kv row, k=d); V tile (B-frag from V^T: n=d, k=kv)
      short8 bk[4][2], bv[4][2];
      #pragma unroll
      for (int ni = 0; ni < 4; ni++)
        #pragma unroll
        for (int ks = 0; ks < 2; ks++)
          bk[ni][ks] = *(const short8*)(kp + (size_t)(kv0 + ni*16 + lr)*HD + ks*32 + lg*8);
      #pragma unroll
      for (int ni = 0; ni < 4; ni++)
        #pragma unroll
        for (int ks = 0; ks < 2; ks++)
          bv[ni][ks] = *(const short8*)(vp + (size_t)(ni*16 + lr)*SEQ + kv0 + ks*32 + lg*8);

      // ---- S = Q K^T ----
      f32x4 s[4] = {};
      #pragma unroll
      for (int ni = 0; ni < 4; ni++){
        s[ni] = __builtin_amdgcn_mfma_f32_16x16x32_bf16(aq[0], bk[ni][0], s[ni], 0,0,0);
        s[ni] = __builtin_amdgcn_mfma_f32_16x16x32_bf16(aq[1], bk[ni][1], s[ni], 0,0,0);
      }

      // ---- scale (+ causal mask on the final, diagonal step only) ----
      if (kvb == nkv-1){
        #pragma unroll
        for (int ni = 0; ni < 4; ni++)
          #pragma unroll
          for (int jj = 0; jj < 4; jj++){
            int row = q0 + lg*4 + jj;
            int col = kv0 + ni*16 + lr;
            float v = s[ni][jj] * SC;
            s[ni][jj] = (col <= row) ? v : -1e30f;
          }
      } else {
        #pragma unroll
        for (int ni = 0; ni < 4; ni++)
          #pragma unroll
          for (int jj = 0; jj < 4; jj++)
            s[ni][jj] *= SC;
      }

      // ---- online softmax (log2 domain) ----
      float alpha[4], mnew[4];
      #pragma unroll
      for (int jj = 0; jj < 4; jj++){
        float v = fmaxf(fmaxf(s[0][jj], s[1][jj]), fmaxf(s[2][jj], s[3][jj]));
        v = fmaxf(v, __shfl_xor(v, 1));
        v = fmaxf(v, __shfl_xor(v, 2));
        v = fmaxf(v, __shfl_xor(v, 4));
        v = fmaxf(v, __shfl_xor(v, 8));
        float mn = fmaxf(mrow[jj], v);
        alpha[jj] = __builtin_amdgcn_exp2f(mrow[jj] - mn);
        mnew[jj] = mn;
        mrow[jj] = mn;
      }

      // P = exp2(s - mnew): row sums + bf16 P to wave-local LDS (swizzled)
      float psum[4] = {};
      #pragma unroll
      for (int ni = 0; ni < 4; ni++)
        #pragma unroll
        for (int jj = 0; jj < 4; jj++){
          float p = __builtin_amdgcn_exp2f(s[ni][jj] - mnew[jj]);
          psum[jj] += p;
          int row = lg*4 + jj;
          int colb = (ni*16 + lr)*2;
          *(u16*)(Ps + row*128 + (colb ^ ((row&7)<<4))) = f2bf(p);
        }
      #pragma unroll
      for (int jj = 0; jj < 4; jj++){
        float v = psum[jj];
        v += __shfl_xor(v, 1);
        v += __shfl_xor(v, 2);
        v += __shfl_xor(v, 4);
        v += __shfl_xor(v, 8);
        lsum[jj] = lsum[jj]*alpha[jj] + v;
      }
      #pragma unroll
      for (int ni = 0; ni < 4; ni++)
        #pragma unroll
        for (int jj = 0; jj < 4; jj++)
          o[ni][jj] *= alpha[jj];

      // ---- O += P V (P A-frags from wave-local LDS; lgkmcnt only, no barrier) ----
      short8 pa[2];
      #pragma unroll
      for (int ks = 0; ks < 2; ks++){
        int byt = (ks*64 + lg*16) ^ ((lr&7)<<4);
        pa[ks] = *(const short8*)(Ps + lr*128 + byt);
      }
      #pragma unroll
      for (int ni = 0; ni < 4; ni++){
        o[ni] = __builtin_amdgcn_mfma_f32_16x16x32_bf16(pa[0], bv[ni][0], o[ni], 0,0,0);
        o[ni] = __builtin_amdgcn_mfma_f32_16x16x32_bf16(pa[1], bv[ni][1], o[ni], 0,0,0);
      }
    }

    // epilogue: aout[b][s][h*64+d] bf16
    #pragma unroll
    for (int jj = 0; jj < 4; jj++){
      float inv = 1.0f / lsum[jj];
      int qrow = q0 + lg*4 + jj;
      #pragma unroll
      for (int ni = 0; ni < 4; ni++)
        aout[((size_t)b_*SEQ + qrow)*D_MODEL + h*HD + ni*16 + lr] = f2bf(o[ni][jj]*inv);
    }
  }
}

extern "C" void kernel_launch(void* const* d_in, const int* in_sizes, int n_in,
                              void* d_out, int out_size, void* d_ws, size_t ws_size,
                              hipStream_t stream)
{
  const float* x    = (const float*)d_in[0];
  const float* Wqkv = (const float*)d_in[1];
  const float* bqkv = (const float*)d_in[2];
  const float* Wout = (const float*)d_in[3];
  const float* bout = (const float*)d_in[4];
  float* out = (float*)d_out;
  char* ws = (char*)d_ws;

  // workspace layout (bytes)
  u16* x_bf   = (u16*)(ws + 0);          // 8192x768   bf16 = 12,582,912
  u16* wqkv_t = (u16*)(ws + 12582912);   // 2304x768   bf16 =  3,538,944
  u16* wout_t = (u16*)(ws + 16121856);   //  768x768   bf16 =  1,179,648
  u16* qb     = (u16*)(ws + 17301504);   // [48][2048][64]  = 12,582,912
  u16* kb     = (u16*)(ws + 29884416);   // [48][2048][64]  = 12,582,912
  u16* vtb    = (u16*)(ws + 42467328);   // [48][64][2048]  = 12,582,912
  u16* attnb  = (u16*)(ws + 55050240);   // 8192x768   bf16 = 12,582,912

  cast4_kernel<<<6144, 256, 0, stream>>>(x, x_bf, (BATCH*SEQ*D_MODEL)/4);
  transpose_cast_kernel<<<dim3(12, 36), 256, 0, stream>>>(Wqkv, wqkv_t, 768, 2304);
  transpose_cast_kernel<<<dim3(12, 12), 256, 0, stream>>>(Wout, wout_t, 768, 768);

  gemm_bf16<1><<<dim3(64, 18), 256, 0, stream>>>(x_bf, wqkv_t, bqkv, nullptr,
                                                 qb, kb, vtb, MROWS, 3*D_MODEL, D_MODEL);

  attn_kernel<<<768, 256, 0, stream>>>(qb, kb, vtb, attnb);

  gemm_bf16<0><<<dim3(64, 6), 256, 0, stream>>>(attnb, wout_t, bout, out,
                                                nullptr, nullptr, nullptr, MROWS, D_MODEL, D_MODEL);
}

// Round 5
// 264.157 us; speedup vs baseline: 1.0081x; 1.0081x over previous
//
#include <hip/hip_runtime.h>
#include <hip/hip_bf16.h>

// Problem constants
#define D_MODEL 768
#define NH 12
#define HD 64
#define BATCH 4
#define SEQ 2048
#define BHN (BATCH*NH)        // 48
#define MROWS (BATCH*SEQ)     // 8192

typedef unsigned short u16;
typedef unsigned int u32;
typedef __attribute__((ext_vector_type(8))) short short8;
typedef __attribute__((ext_vector_type(4))) float f32x4;

__device__ inline u16 f2bf(float f){
  union { __hip_bfloat16 h; u16 u; } cv; cv.h = __float2bfloat16(f); return cv.u;
}

// async global->LDS, 16B per lane. LDS dest = wave-uniform base + lane*16.
__device__ inline void async_copy16(const void* g, void* l){
  __builtin_amdgcn_global_load_lds(
      (const __attribute__((address_space(1))) void*)g,
      (__attribute__((address_space(3))) void*)l, 16, 0, 0);
}

// ---------------- cast fp32 -> bf16, vectorized x4 ----------------
__global__ void cast4_kernel(const float* __restrict__ in, u16* __restrict__ out, int n4){
  int i = blockIdx.x*blockDim.x + threadIdx.x;
  if (i < n4){
    const float4 v = ((const float4*)in)[i];
    ushort4 o;
    o.x = f2bf(v.x); o.y = f2bf(v.y); o.z = f2bf(v.z); o.w = f2bf(v.w);
    ((ushort4*)out)[i] = o;
  }
}

// ---------------- transpose + cast: W[K][N] fp32 -> Wt[N][K] bf16 ----------------
__global__ void transpose_cast_kernel(const float* __restrict__ w, u16* __restrict__ wt,
                                      int K, int N){
  __shared__ u16 tile[64][65];
  int k0 = blockIdx.x*64, n0 = blockIdx.y*64;
  int c = threadIdx.x & 63, r0 = threadIdx.x >> 6;
  #pragma unroll
  for (int r = r0; r < 64; r += 4)
    tile[c][r] = f2bf(w[(size_t)(k0+r)*N + n0 + c]);
  __syncthreads();
  #pragma unroll
  for (int r = r0; r < 64; r += 4)
    wt[(size_t)(n0+r)*K + k0 + c] = tile[r][c];
}

// ---------------- bf16 GEMM: C[M,N] = A[M,K] @ Bt[N,K]^T ----------------
// 128x128 tile, BK=32, double-buffered LDS, 2-phase prefetch.
template<int EPI>
__launch_bounds__(256)
__global__ void gemm_bf16(const u16* __restrict__ A, const u16* __restrict__ Bt,
                          const float* __restrict__ bias, float* __restrict__ outf,
                          u16* __restrict__ oq, u16* __restrict__ ok, u16* __restrict__ ovt,
                          int M, int N, int K)
{
  __shared__ alignas(16) char smem[32768];   // As0,As1,Bs0,Bs1: 8KB each
  const int tid = threadIdx.x, wave = tid>>6, lane = tid&63;
  const int lr = lane&15, lg = lane>>4;
  const int m0 = blockIdx.x*128, n0 = blockIdx.y*128;
  const int wr = (wave>>1)*64, wc = (wave&1)*64;
  f32x4 acc[4][4] = {};
  const int srow = wave*32 + (lane>>2);   // staging row (+i*16)
  const int schk = lane&3;                // 16B chunk within 64B row

  auto stage = [&](int kt, int buf){
    char* Ab = smem + buf*8192;
    char* Bb = smem + 16384 + buf*8192;
    #pragma unroll
    for (int i = 0; i < 2; i++){
      int r = srow + i*16;
      async_copy16(A  + (size_t)(m0 + r)*K + kt + schk*8, Ab + (wave*32 + i*16)*64);
      async_copy16(Bt + (size_t)(n0 + r)*K + kt + schk*8, Bb + (wave*32 + i*16)*64);
    }
  };

  const int NT = K >> 5;
  stage(0, 0);
  for (int t = 0; t < NT; t++){
    const int c = t & 1;
    asm volatile("s_waitcnt vmcnt(0)" ::: "memory");
    __builtin_amdgcn_s_barrier();
    if (t+1 < NT) stage((t+1)<<5, c^1);

    const char* Ac = smem + c*8192;
    const char* Bc = smem + 16384 + c*8192;
    short8 a[4], b[4];
    #pragma unroll
    for (int mi = 0; mi < 4; mi++)
      a[mi] = *(const short8*)(Ac + (wr + mi*16 + lr)*64 + lg*16);
    #pragma unroll
    for (int ni = 0; ni < 4; ni++)
      b[ni] = *(const short8*)(Bc + (wc + ni*16 + lr)*64 + lg*16);
    #pragma unroll
    for (int mi = 0; mi < 4; mi++)
      #pragma unroll
      for (int ni = 0; ni < 4; ni++)
        acc[mi][ni] = __builtin_amdgcn_mfma_f32_16x16x32_bf16(a[mi], b[ni], acc[mi][ni], 0, 0, 0);
  }

  // epilogue: C row = (lane>>4)*4 + j, col = lane&15  [verified C/D layout]
  #pragma unroll
  for (int mi = 0; mi < 4; mi++)
  #pragma unroll
  for (int ni = 0; ni < 4; ni++)
  #pragma unroll
  for (int j = 0; j < 4; j++){
    int m = m0 + wr + mi*16 + lg*4 + j;
    int n = n0 + wc + ni*16 + lr;
    float v = acc[mi][ni][j] + bias[n];
    if (EPI == 0){
      outf[(size_t)m*N + n] = v;
    } else {
      int b_ = m >> 11, s = m & 2047;
      int t  = (n >= 1536) ? 2 : (n >= 768 ? 1 : 0);
      int hn = n - t*768;
      int h = hn >> 6, d = hn & 63;
      size_t base = (size_t)(b_*NH + h);
      if (t == 0)      oq [(base*SEQ + s)*HD + d] = f2bf(v * 0.1803368801f); // fold 0.125*log2e into Q
      else if (t == 1) ok [(base*SEQ + s)*HD + d] = f2bf(v);
      else             ovt[(base*HD + d)*SEQ + s] = f2bf(v);   // V stored transposed
    }
  }
}

// ---------------- flash attention: swapped-operand, barrier-free ----------------
// 768 blocks x 256 threads = 3072 waves (12/CU, 3/SIMD via launch_bounds).
// Each wave owns 16 q-rows; pair (p,127-p) -> uniform 33 KV64-steps.
// Swapped QK: S^T = mfma(K, Q^T) so each lane holds one q-row (q=lane&15);
// softmax state is per-lane scalar; row-reduce = local tree + 2 shfl.
// PV swapped too: O^T = mfma(V^T, P^T). P C-frag -> B-frag relayout is a pure
// lg-group word permutation through 2KB wave-local LDS: 8 ds_write_b32 + 2
// ds_read_b128 per step. No block barriers anywhere.
__launch_bounds__(256, 3)
__global__ void attn_kernel(const u16* __restrict__ q, const u16* __restrict__ k,
                            const u16* __restrict__ vt, u16* __restrict__ aout)
{
  __shared__ alignas(16) char Ps_all[8192];  // 4 waves x 2KB (P^T B-frag: [ks][lane][16B])
  const int b1 = blockIdx.x;                 // 0..767
  const int xcd = b1 & 7, grp = b1 >> 3;     // grp 0..95
  const int bh = xcd*6 + (grp >> 4);         // 6 heads per XCD
  const int pairblk = grp & 15;              // 0..15
  const int tid = threadIdx.x, wave = tid>>6, lane = tid&63;
  const int pr = pairblk*4 + wave;           // pair index 0..63
  const int lr = lane&15, lg = lane>>4;
  char* Ps = Ps_all + wave*2048;
  const int b_ = bh / NH, h = bh % NH;
  const u16* qp = q  + (size_t)bh*SEQ*HD;
  const u16* kp = k  + (size_t)bh*SEQ*HD;
  const u16* vp = vt + (size_t)bh*HD*SEQ;

  // LDS write offsets for the 8 P-frag words: value W[ni][wj] (pack of
  // p[ni][2wj],p[ni][2wj+1]) goes to frag ks=ni>>1, target group
  // lg_t=((ni&1)<<1)|(lg>>1), slot=((lg&1)<<1)|wj.
  int poff[4];
  #pragma unroll
  for (int ni = 0; ni < 4; ni++){
    int lg_t = ((ni&1)<<1) | (lg>>1);
    poff[ni] = (ni>>1)*1024 + (lr + 16*lg_t)*16 + ((lg&1)<<3);  // wj=0; wj=1 at +4
  }

  #pragma unroll 1
  for (int half = 0; half < 2; half++){
    const int t = half ? (127 - pr) : pr;    // 16-row tile index 0..127
    const int q0 = t*16;
    const int nkv = (t >> 2) + 1;            // KV64 steps
    const int qrow = q0 + lr;                // this lane's q-row

    // Q^T B-frag: lane(q=lr, kh=lg) holds d = ks*32 + lg*8 + e
    short8 bq[2];
    #pragma unroll
    for (int ks = 0; ks < 2; ks++)
      bq[ks] = *(const short8*)(qp + (size_t)qrow*HD + ks*32 + lg*8);

    float mrow = -INFINITY, lsum = 0.f;
    f32x4 o[4] = {};   // O^T: d = ni*16 + lg*4 + jj, q = lr

    // prologue: K tile 0 -> A-frags (m=kv: ni*16+lr, k=d: ks*32+lg*8+e)
    short8 bk[4][2];
    #pragma unroll
    for (int ni = 0; ni < 4; ni++)
      #pragma unroll
      for (int ks = 0; ks < 2; ks++)
        bk[ni][ks] = *(const short8*)(kp + (size_t)(ni*16 + lr)*HD + ks*32 + lg*8);

    #pragma unroll 1
    for (int kvb = 0; kvb < nkv; kvb++){
      const int kv0 = kvb*64;

      // V^T A-frags for this step (m=d: ni*16+lr, k=kv: ks*32+lg*8+e)
      short8 av[4][2];
      #pragma unroll
      for (int ni = 0; ni < 4; ni++)
        #pragma unroll
        for (int ks = 0; ks < 2; ks++)
          av[ni][ks] = *(const short8*)(vp + (size_t)(ni*16 + lr)*SEQ + kv0 + ks*32 + lg*8);

      // ---- S^T = K Q^T : lane holds s[ni][jj] = S[q=lr][kv = kv0+ni*16+lg*4+jj]
      f32x4 s[4] = {};
      #pragma unroll
      for (int ni = 0; ni < 4; ni++){
        s[ni] = __builtin_amdgcn_mfma_f32_16x16x32_bf16(bk[ni][0], bq[0], s[ni], 0,0,0);
        s[ni] = __builtin_amdgcn_mfma_f32_16x16x32_bf16(bk[ni][1], bq[1], s[ni], 0,0,0);
      }

      // reload K with next tile (regs free after QK; latency hides under softmax+PV)
      if (kvb+1 < nkv){
        #pragma unroll
        for (int ni = 0; ni < 4; ni++)
          #pragma unroll
          for (int ks = 0; ks < 2; ks++)
            bk[ni][ks] = *(const short8*)(kp + (size_t)(kv0 + 64 + ni*16 + lr)*HD + ks*32 + lg*8);
      }

      // ---- causal mask (diagonal step only; Q pre-scaled, exp2 domain) ----
      if (kvb == nkv-1){
        #pragma unroll
        for (int ni = 0; ni < 4; ni++)
          #pragma unroll
          for (int jj = 0; jj < 4; jj++){
            int col = kv0 + ni*16 + lg*4 + jj;
            if (col > qrow) s[ni][jj] = -1e30f;
          }
      }

      // ---- online softmax: per-lane scalar state ----
      float v01 = fmaxf(fmaxf(s[0][0], s[0][1]), fmaxf(s[0][2], s[0][3]));
      float v1  = fmaxf(fmaxf(s[1][0], s[1][1]), fmaxf(s[1][2], s[1][3]));
      float v2  = fmaxf(fmaxf(s[2][0], s[2][1]), fmaxf(s[2][2], s[2][3]));
      float v3  = fmaxf(fmaxf(s[3][0], s[3][1]), fmaxf(s[3][2], s[3][3]));
      float v = fmaxf(fmaxf(v01, v1), fmaxf(v2, v3));
      v = fmaxf(v, __shfl_xor(v, 16));
      v = fmaxf(v, __shfl_xor(v, 32));
      float mn = fmaxf(mrow, v);
      float alpha = __builtin_amdgcn_exp2f(mrow - mn);
      mrow = mn;

      float p[4][4];
      float psum = 0.f;
      #pragma unroll
      for (int ni = 0; ni < 4; ni++)
        #pragma unroll
        for (int jj = 0; jj < 4; jj++){
          float pe = __builtin_amdgcn_exp2f(s[ni][jj] - mn);
          p[ni][jj] = pe;
          psum += pe;
        }
      psum += __shfl_xor(psum, 16);
      psum += __shfl_xor(psum, 32);
      lsum = lsum*alpha + psum;
      #pragma unroll
      for (int ni = 0; ni < 4; ni++)
        #pragma unroll
        for (int jj = 0; jj < 4; jj++)
          o[ni][jj] *= alpha;

      // ---- P relayout: pack pairs to bf16 words, scatter into B-frag LDS ----
      #pragma unroll
      for (int ni = 0; ni < 4; ni++){
        u32 w0 = (u32)f2bf(p[ni][0]) | ((u32)f2bf(p[ni][1]) << 16);
        u32 w1 = (u32)f2bf(p[ni][2]) | ((u32)f2bf(p[ni][3]) << 16);
        *(u32*)(Ps + poff[ni])     = w0;
        *(u32*)(Ps + poff[ni] + 4) = w1;
      }
      short8 pb0 = *(const short8*)(Ps + lane*16);
      short8 pb1 = *(const short8*)(Ps + 1024 + lane*16);

      // ---- O^T += V^T P^T ----
      #pragma unroll
      for (int ni = 0; ni < 4; ni++){
        o[ni] = __builtin_amdgcn_mfma_f32_16x16x32_bf16(av[ni][0], pb0, o[ni], 0,0,0);
        o[ni] = __builtin_amdgcn_mfma_f32_16x16x32_bf16(av[ni][1], pb1, o[ni], 0,0,0);
      }
    }

    // epilogue: lane writes its q-row: d = ni*16 + lg*4 + jj
    float inv = 1.0f / lsum;
    u16* orow = aout + ((size_t)b_*SEQ + qrow)*D_MODEL + h*HD;
    #pragma unroll
    for (int ni = 0; ni < 4; ni++){
      ushort4 w;
      w.x = f2bf(o[ni][0]*inv);
      w.y = f2bf(o[ni][1]*inv);
      w.z = f2bf(o[ni][2]*inv);
      w.w = f2bf(o[ni][3]*inv);
      *(ushort4*)(orow + ni*16 + lg*4) = w;
    }
  }
}

extern "C" void kernel_launch(void* const* d_in, const int* in_sizes, int n_in,
                              void* d_out, int out_size, void* d_ws, size_t ws_size,
                              hipStream_t stream)
{
  const float* x    = (const float*)d_in[0];
  const float* Wqkv = (const float*)d_in[1];
  const float* bqkv = (const float*)d_in[2];
  const float* Wout = (const float*)d_in[3];
  const float* bout = (const float*)d_in[4];
  float* out = (float*)d_out;
  char* ws = (char*)d_ws;

  // workspace layout (bytes)
  u16* x_bf   = (u16*)(ws + 0);          // 8192x768   bf16 = 12,582,912
  u16* wqkv_t = (u16*)(ws + 12582912);   // 2304x768   bf16 =  3,538,944
  u16* wout_t = (u16*)(ws + 16121856);   //  768x768   bf16 =  1,179,648
  u16* qb     = (u16*)(ws + 17301504);   // [48][2048][64]  = 12,582,912
  u16* kb     = (u16*)(ws + 29884416);   // [48][2048][64]  = 12,582,912
  u16* vtb    = (u16*)(ws + 42467328);   // [48][64][2048]  = 12,582,912
  u16* attnb  = (u16*)(ws + 55050240);   // 8192x768   bf16 = 12,582,912

  cast4_kernel<<<6144, 256, 0, stream>>>(x, x_bf, (BATCH*SEQ*D_MODEL)/4);
  transpose_cast_kernel<<<dim3(12, 36), 256, 0, stream>>>(Wqkv, wqkv_t, 768, 2304);
  transpose_cast_kernel<<<dim3(12, 12), 256, 0, stream>>>(Wout, wout_t, 768, 768);

  gemm_bf16<1><<<dim3(64, 18), 256, 0, stream>>>(x_bf, wqkv_t, bqkv, nullptr,
                                                 qb, kb, vtb, MROWS, 3*D_MODEL, D_MODEL);

  attn_kernel<<<768, 256, 0, stream>>>(qb, kb, vtb, attnb);

  gemm_bf16<0><<<dim3(64, 6), 256, 0, stream>>>(attnb, wout_t, bout, out,
                                                nullptr, nullptr, nullptr, MROWS, D_MODEL, D_MODEL);
}

// Round 6
// 157.623 us; speedup vs baseline: 1.6895x; 1.6759x over previous
//
#include <hip/hip_runtime.h>
#include <hip/hip_bf16.h>

// Problem constants
#define D_MODEL 768
#define NH 12
#define HD 64
#define BATCH 4
#define SEQ 2048
#define BHN (BATCH*NH)        // 48
#define MROWS (BATCH*SEQ)     // 8192

typedef unsigned short u16;
typedef unsigned int u32;
typedef __attribute__((ext_vector_type(8))) short short8;
typedef __attribute__((ext_vector_type(4))) float f32x4;

__device__ inline u16 f2bf(float f){
  union { __hip_bfloat16 h; u16 u; } cv; cv.h = __float2bfloat16(f); return cv.u;
}
__device__ inline u32 pack_bf2(float a, float b){
  return (u32)f2bf(a) | ((u32)f2bf(b) << 16);
}

// async global->LDS, 16B per lane. LDS dest = wave-uniform base + lane*16.
__device__ inline void async_copy16(const void* g, void* l){
  __builtin_amdgcn_global_load_lds(
      (const __attribute__((address_space(1))) void*)g,
      (__attribute__((address_space(3))) void*)l, 16, 0, 0);
}

// ---------------- cast fp32 -> bf16, vectorized x4 ----------------
__global__ void cast4_kernel(const float* __restrict__ in, u16* __restrict__ out, int n4){
  int i = blockIdx.x*blockDim.x + threadIdx.x;
  if (i < n4){
    const float4 v = ((const float4*)in)[i];
    ushort4 o;
    o.x = f2bf(v.x); o.y = f2bf(v.y); o.z = f2bf(v.z); o.w = f2bf(v.w);
    ((ushort4*)out)[i] = o;
  }
}

// ---------------- transpose + cast: W[K][N] fp32 -> Wt[N][K] bf16 ----------------
__global__ void transpose_cast_kernel(const float* __restrict__ w, u16* __restrict__ wt,
                                      int K, int N){
  __shared__ u16 tile[64][65];
  int k0 = blockIdx.x*64, n0 = blockIdx.y*64;
  int c = threadIdx.x & 63, r0 = threadIdx.x >> 6;
  #pragma unroll
  for (int r = r0; r < 64; r += 4)
    tile[c][r] = f2bf(w[(size_t)(k0+r)*N + n0 + c]);
  __syncthreads();
  #pragma unroll
  for (int r = r0; r < 64; r += 4)
    wt[(size_t)(n0+r)*K + k0 + c] = tile[r][c];
}

// ---------------- bf16 GEMM: C[M,N] = A[M,K] @ Bt[N,K]^T ----------------
// 128x128 tile, BK=32, double-buffered LDS, single-barrier prefetch.
template<int EPI>
__launch_bounds__(256)
__global__ void gemm_bf16(const u16* __restrict__ A, const u16* __restrict__ Bt,
                          const float* __restrict__ bias, float* __restrict__ outf,
                          u16* __restrict__ oq, u16* __restrict__ ok, u16* __restrict__ ovt,
                          int M, int N, int K)
{
  __shared__ alignas(16) char smem[32768];   // As0,As1,Bs0,Bs1: 8KB each
  const int tid = threadIdx.x, wave = tid>>6, lane = tid&63;
  const int lr = lane&15, lg = lane>>4;
  const int m0 = blockIdx.x*128, n0 = blockIdx.y*128;
  const int wr = (wave>>1)*64, wc = (wave&1)*64;
  f32x4 acc[4][4] = {};
  const int srow = wave*32 + (lane>>2);   // staging row (+i*16)
  const int schk = lane&3;                // 16B chunk within 64B row

  auto stage = [&](int kt, int buf){
    char* Ab = smem + buf*8192;
    char* Bb = smem + 16384 + buf*8192;
    #pragma unroll
    for (int i = 0; i < 2; i++){
      int r = srow + i*16;
      async_copy16(A  + (size_t)(m0 + r)*K + kt + schk*8, Ab + (wave*32 + i*16)*64);
      async_copy16(Bt + (size_t)(n0 + r)*K + kt + schk*8, Bb + (wave*32 + i*16)*64);
    }
  };

  const int NT = K >> 5;
  stage(0, 0);
  for (int t = 0; t < NT; t++){
    const int c = t & 1;
    asm volatile("s_waitcnt vmcnt(0)" ::: "memory");
    __builtin_amdgcn_s_barrier();
    if (t+1 < NT) stage((t+1)<<5, c^1);

    const char* Ac = smem + c*8192;
    const char* Bc = smem + 16384 + c*8192;
    short8 a[4], b[4];
    #pragma unroll
    for (int mi = 0; mi < 4; mi++)
      a[mi] = *(const short8*)(Ac + (wr + mi*16 + lr)*64 + lg*16);
    #pragma unroll
    for (int ni = 0; ni < 4; ni++)
      b[ni] = *(const short8*)(Bc + (wc + ni*16 + lr)*64 + lg*16);
    #pragma unroll
    for (int mi = 0; mi < 4; mi++)
      #pragma unroll
      for (int ni = 0; ni < 4; ni++)
        acc[mi][ni] = __builtin_amdgcn_mfma_f32_16x16x32_bf16(a[mi], b[ni], acc[mi][ni], 0, 0, 0);
    asm volatile("s_waitcnt lgkmcnt(0)" ::: "memory");
    __builtin_amdgcn_sched_barrier(0);
    __builtin_amdgcn_s_barrier();
  }

  // epilogue: C row = (lane>>4)*4 + j, col = lane&15  [verified C/D layout]
  #pragma unroll
  for (int mi = 0; mi < 4; mi++)
  #pragma unroll
  for (int ni = 0; ni < 4; ni++)
  #pragma unroll
  for (int j = 0; j < 4; j++){
    int m = m0 + wr + mi*16 + lg*4 + j;
    int n = n0 + wc + ni*16 + lr;
    float v = acc[mi][ni][j] + bias[n];
    if (EPI == 0){
      outf[(size_t)m*N + n] = v;
    } else {
      int b_ = m >> 11, s = m & 2047;
      int t  = (n >= 1536) ? 2 : (n >= 768 ? 1 : 0);
      int hn = n - t*768;
      int h = hn >> 6, d = hn & 63;
      size_t base = (size_t)(b_*NH + h);
      if (t == 0)      oq [(base*SEQ + s)*HD + d] = f2bf(v * 0.1803368801f); // fold 0.125*log2e into Q
      else if (t == 1) ok [(base*SEQ + s)*HD + d] = f2bf(v);
      else             ovt[(base*HD + d)*SEQ + s] = f2bf(v);   // V stored transposed
    }
  }
}

// ---------------- flash attention: shared-KV LDS, swapped-operand ----------------
// 768 blocks x 128 threads (2 waves x 32 q-rows = 64-row tile). Pair (p,31-p)
// -> uniform 33 KV64-steps/block; 3 blocks/CU exactly resident (LDS 42KB).
// K/V staged via global_load_lds into double buffer, m201 single-barrier
// counted pattern. Frag reads conflict-free (source-swizzled col8 ^= row&7).
// Swapped QK (S^T = K*Q^T): per-lane scalar softmax state (2 q-rows/lane).
// P relayout via stride-40 wave-local LDS bounce (<=2-way banks).
__launch_bounds__(128, 2)
__global__ void attn_kernel(const u16* __restrict__ q, const u16* __restrict__ k,
                            const u16* __restrict__ vt, u16* __restrict__ aout)
{
  __shared__ alignas(16) char smem[43008];
  // buf b: K at b*16384, V at b*16384+8192 (rows 128B, col-swizzled)
  // P bounce at 32768 + wave*5120 + h*2560  (64 rows x 40B)

  const int b1 = blockIdx.x;                 // 0..767
  const int xcd = b1 & 7, grp = b1 >> 3;     // grp 0..95
  const int bh = xcd*6 + (grp >> 4);         // 6 heads per XCD (L2 locality)
  const int pairblk = grp & 15;              // pair 0..15
  const int tid = threadIdx.x, wave = tid>>6, lane = tid&63;
  const int lr = lane&15, lg = lane>>4;
  const int b_ = bh / NH, h_ = bh % NH;
  const u16* qp = q  + (size_t)bh*SEQ*HD;
  const u16* kp = k  + (size_t)bh*SEQ*HD;
  const u16* vp = vt + (size_t)bh*HD*SEQ;
  char* Pw = smem + 32768 + wave*5120;
  const int fswz = (lr&7)<<4;
  const int c8s = (lane&7) ^ (lane>>3);      // staging source col swizzle

  auto stageKV = [&](int kv0, int buf){
    char* Kb = smem + buf*16384;
    char* Vb = Kb + 8192;
    #pragma unroll
    for (int r = 0; r < 4; r++){
      int row = r*16 + wave*8 + (lane>>3);
      async_copy16(kp + (size_t)(kv0 + row)*HD + c8s*8, Kb + r*2048 + wave*1024);
      async_copy16(vp + (size_t)row*SEQ + kv0 + c8s*8,  Vb + r*2048 + wave*1024);
    }
  };

  #pragma unroll 1
  for (int half = 0; half < 2; half++){
    const int t = half ? (31 - pairblk) : pairblk;   // 64-row tile 0..31
    const int nkv = t + 1;
    const int q0w = t*64 + wave*32;

    // Q^T B-frags: lane holds Q[q = q0w+h*16+lr][d = ks*32+lg*8+e]
    short8 bq[2][2];
    #pragma unroll
    for (int h = 0; h < 2; h++)
      #pragma unroll
      for (int ks = 0; ks < 2; ks++)
        bq[h][ks] = *(const short8*)(qp + (size_t)(q0w + h*16 + lr)*HD + ks*32 + lg*8);

    float mrow[2] = {-INFINITY, -INFINITY};
    float lsum[2] = {0.f, 0.f};
    f32x4 o[4][2] = {};   // O^T: d = ni*16+lg*4+jj, q = h*16+lr

    // sync before overwriting buf0 (prev half readers), then prologue stage
    asm volatile("s_waitcnt vmcnt(0) lgkmcnt(0)" ::: "memory");
    __builtin_amdgcn_sched_barrier(0);
    __builtin_amdgcn_s_barrier();
    stageKV(0, 0);

    #pragma unroll 1
    for (int kvb = 0; kvb < nkv; kvb++){
      const int c = kvb & 1;
      const int kv0 = kvb*64;
      // my stage(kvb) + my prior LDS reads complete -> barrier -> all staged
      asm volatile("s_waitcnt vmcnt(0) lgkmcnt(0)" ::: "memory");
      __builtin_amdgcn_sched_barrier(0);
      __builtin_amdgcn_s_barrier();
      if (kvb+1 < nkv) stageKV(kv0 + 64, c^1);

      const char* Kb = smem + c*16384;
      const char* Vb = Kb + 8192;

      // ---- S^T = K Q^T : lane holds s[ni][h][jj] = S[q=h*16+lr][kv0+ni*16+lg*4+jj]
      f32x4 s[4][2] = {};
      #pragma unroll
      for (int ni = 0; ni < 4; ni++){
        short8 k0 = *(const short8*)(Kb + (ni*16+lr)*128 + ((lg*16) ^ fswz));
        short8 k1 = *(const short8*)(Kb + (ni*16+lr)*128 + ((64 + lg*16) ^ fswz));
        #pragma unroll
        for (int h = 0; h < 2; h++){
          s[ni][h] = __builtin_amdgcn_mfma_f32_16x16x32_bf16(k0, bq[h][0], s[ni][h], 0,0,0);
          s[ni][h] = __builtin_amdgcn_mfma_f32_16x16x32_bf16(k1, bq[h][1], s[ni][h], 0,0,0);
        }
      }

      // ---- causal mask (diagonal step only; Q pre-scaled by 0.125*log2e) ----
      if (kvb == nkv-1){
        #pragma unroll
        for (int ni = 0; ni < 4; ni++)
          #pragma unroll
          for (int h = 0; h < 2; h++)
            #pragma unroll
            for (int jj = 0; jj < 4; jj++){
              int col = kv0 + ni*16 + lg*4 + jj;
              int qrow = q0w + h*16 + lr;
              if (col > qrow) s[ni][h][jj] = -1e30f;
            }
      }

      // ---- online softmax (per-lane scalars, 2 q-rows) + P pack/bounce ----
      #pragma unroll
      for (int h = 0; h < 2; h++){
        float v0 = fmaxf(fmaxf(s[0][h][0], s[0][h][1]), fmaxf(s[0][h][2], s[0][h][3]));
        float v1 = fmaxf(fmaxf(s[1][h][0], s[1][h][1]), fmaxf(s[1][h][2], s[1][h][3]));
        float v2 = fmaxf(fmaxf(s[2][h][0], s[2][h][1]), fmaxf(s[2][h][2], s[2][h][3]));
        float v3 = fmaxf(fmaxf(s[3][h][0], s[3][h][1]), fmaxf(s[3][h][2], s[3][h][3]));
        float v = fmaxf(fmaxf(v0, v1), fmaxf(v2, v3));
        v = fmaxf(v, __shfl_xor(v, 16));
        v = fmaxf(v, __shfl_xor(v, 32));
        float mn = fmaxf(mrow[h], v);
        float alpha = __builtin_amdgcn_exp2f(mrow[h] - mn);
        mrow[h] = mn;

        char* hb = Pw + h*2560;
        float psum = 0.f;
        #pragma unroll
        for (int ni = 0; ni < 4; ni++){
          float p0 = __builtin_amdgcn_exp2f(s[ni][h][0] - mn);
          float p1 = __builtin_amdgcn_exp2f(s[ni][h][1] - mn);
          float p2 = __builtin_amdgcn_exp2f(s[ni][h][2] - mn);
          float p3 = __builtin_amdgcn_exp2f(s[ni][h][3] - mn);
          psum += (p0+p1) + (p2+p3);
          int tl = lr + 16*(((ni&1)<<1) | (lg>>1));
          int wb = ((ni>>1)<<2) | ((lg&1)<<1);
          *(u32*)(hb + tl*40 + wb*4)     = pack_bf2(p0, p1);
          *(u32*)(hb + tl*40 + wb*4 + 4) = pack_bf2(p2, p3);
        }
        psum += __shfl_xor(psum, 16);
        psum += __shfl_xor(psum, 32);
        lsum[h] = lsum[h]*alpha + psum;
        #pragma unroll
        for (int ni = 0; ni < 4; ni++)
          #pragma unroll
          for (int jj = 0; jj < 4; jj++)
            o[ni][h][jj] *= alpha;
      }

      // ---- read P^T B-frags (addr = lane*40 + ks*16, contiguous) ----
      union { u32 w[4]; short8 v; } pb[2][2];
      #pragma unroll
      for (int h = 0; h < 2; h++)
        #pragma unroll
        for (int ks = 0; ks < 2; ks++){
          const char* hb = Pw + h*2560 + (size_t)lane*40 + ks*16;
          pb[h][ks].w[0] = *(const u32*)(hb);
          pb[h][ks].w[1] = *(const u32*)(hb + 4);
          pb[h][ks].w[2] = *(const u32*)(hb + 8);
          pb[h][ks].w[3] = *(const u32*)(hb + 12);
        }

      // ---- O^T += V^T P^T ----
      #pragma unroll
      for (int ni = 0; ni < 4; ni++){
        short8 v0 = *(const short8*)(Vb + (ni*16+lr)*128 + ((lg*16) ^ fswz));
        short8 v1 = *(const short8*)(Vb + (ni*16+lr)*128 + ((64 + lg*16) ^ fswz));
        #pragma unroll
        for (int h = 0; h < 2; h++){
          o[ni][h] = __builtin_amdgcn_mfma_f32_16x16x32_bf16(v0, pb[h][0].v, o[ni][h], 0,0,0);
          o[ni][h] = __builtin_amdgcn_mfma_f32_16x16x32_bf16(v1, pb[h][1].v, o[ni][h], 0,0,0);
        }
      }
      asm volatile("s_waitcnt lgkmcnt(0)" ::: "memory");
      __builtin_amdgcn_sched_barrier(0);
    }

    // epilogue: lane writes its two q-rows
    #pragma unroll
    for (int h = 0; h < 2; h++){
      float inv = 1.0f / lsum[h];
      u16* orow = aout + ((size_t)b_*SEQ + q0w + h*16 + lr)*D_MODEL + h_*HD;
      #pragma unroll
      for (int ni = 0; ni < 4; ni++){
        ushort4 w;
        w.x = f2bf(o[ni][h][0]*inv);
        w.y = f2bf(o[ni][h][1]*inv);
        w.z = f2bf(o[ni][h][2]*inv);
        w.w = f2bf(o[ni][h][3]*inv);
        *(ushort4*)(orow + ni*16 + lg*4) = w;
      }
    }
  }
}

extern "C" void kernel_launch(void* const* d_in, const int* in_sizes, int n_in,
                              void* d_out, int out_size, void* d_ws, size_t ws_size,
                              hipStream_t stream)
{
  const float* x    = (const float*)d_in[0];
  const float* Wqkv = (const float*)d_in[1];
  const float* bqkv = (const float*)d_in[2];
  const float* Wout = (const float*)d_in[3];
  const float* bout = (const float*)d_in[4];
  float* out = (float*)d_out;
  char* ws = (char*)d_ws;

  // workspace layout (bytes)
  u16* x_bf   = (u16*)(ws + 0);          // 8192x768   bf16 = 12,582,912
  u16* wqkv_t = (u16*)(ws + 12582912);   // 2304x768   bf16 =  3,538,944
  u16* wout_t = (u16*)(ws + 16121856);   //  768x768   bf16 =  1,179,648
  u16* qb     = (u16*)(ws + 17301504);   // [48][2048][64]  = 12,582,912
  u16* kb     = (u16*)(ws + 29884416);   // [48][2048][64]  = 12,582,912
  u16* vtb    = (u16*)(ws + 42467328);   // [48][64][2048]  = 12,582,912
  u16* attnb  = (u16*)(ws + 55050240);   // 8192x768   bf16 = 12,582,912

  cast4_kernel<<<6144, 256, 0, stream>>>(x, x_bf, (BATCH*SEQ*D_MODEL)/4);
  transpose_cast_kernel<<<dim3(12, 36), 256, 0, stream>>>(Wqkv, wqkv_t, 768, 2304);
  transpose_cast_kernel<<<dim3(12, 12), 256, 0, stream>>>(Wout, wout_t, 768, 768);

  gemm_bf16<1><<<dim3(64, 18), 256, 0, stream>>>(x_bf, wqkv_t, bqkv, nullptr,
                                                 qb, kb, vtb, MROWS, 3*D_MODEL, D_MODEL);

  attn_kernel<<<768, 128, 0, stream>>>(qb, kb, vtb, attnb);

  gemm_bf16<0><<<dim3(64, 6), 256, 0, stream>>>(attnb, wout_t, bout, out,
                                                nullptr, nullptr, nullptr, MROWS, D_MODEL, D_MODEL);
}

// Round 7
// 150.748 us; speedup vs baseline: 1.7666x; 1.0456x over previous
//
#include <hip/hip_runtime.h>
#include <hip/hip_bf16.h>

// Problem constants
#define D_MODEL 768
#define NH 12
#define HD 64
#define BATCH 4
#define SEQ 2048
#define BHN (BATCH*NH)        // 48
#define MROWS (BATCH*SEQ)     // 8192

typedef unsigned short u16;
typedef unsigned int u32;
typedef __attribute__((ext_vector_type(8))) short short8;
typedef __attribute__((ext_vector_type(4))) float f32x4;

__device__ inline u16 f2bf(float f){
  union { __hip_bfloat16 h; u16 u; } cv; cv.h = __float2bfloat16(f); return cv.u;
}
__device__ inline u32 pack_bf2(float a, float b){
  return (u32)f2bf(a) | ((u32)f2bf(b) << 16);
}

// async global->LDS, 16B per lane. LDS dest = wave-uniform base + lane*16.
__device__ inline void async_copy16(const void* g, void* l){
  __builtin_amdgcn_global_load_lds(
      (const __attribute__((address_space(1))) void*)g,
      (__attribute__((address_space(3))) void*)l, 16, 0, 0);
}

// ---------------- cast fp32 -> bf16, vectorized x4 ----------------
__global__ void cast4_kernel(const float* __restrict__ in, u16* __restrict__ out, int n4){
  int i = blockIdx.x*blockDim.x + threadIdx.x;
  if (i < n4){
    const float4 v = ((const float4*)in)[i];
    ushort4 o;
    o.x = f2bf(v.x); o.y = f2bf(v.y); o.z = f2bf(v.z); o.w = f2bf(v.w);
    ((ushort4*)out)[i] = o;
  }
}

// ---------------- transpose + cast: W[K][N] fp32 -> Wt[N][K] bf16 ----------------
__global__ void transpose_cast_kernel(const float* __restrict__ w, u16* __restrict__ wt,
                                      int K, int N){
  __shared__ u16 tile[64][65];
  int k0 = blockIdx.x*64, n0 = blockIdx.y*64;
  int c = threadIdx.x & 63, r0 = threadIdx.x >> 6;
  #pragma unroll
  for (int r = r0; r < 64; r += 4)
    tile[c][r] = f2bf(w[(size_t)(k0+r)*N + n0 + c]);
  __syncthreads();
  #pragma unroll
  for (int r = r0; r < 64; r += 4)
    wt[(size_t)(n0+r)*K + k0 + c] = tile[r][c];
}

// ---------------- bf16 GEMM: C[M,N] = A[M,K] @ Bt[N,K]^T ----------------
// 128x128 tile, BK=32, double-buffered LDS, single-barrier prefetch.
template<int EPI>
__launch_bounds__(256)
__global__ void gemm_bf16(const u16* __restrict__ A, const u16* __restrict__ Bt,
                          const float* __restrict__ bias, float* __restrict__ outf,
                          u16* __restrict__ oq, u16* __restrict__ ok, u16* __restrict__ ovt,
                          int M, int N, int K)
{
  __shared__ alignas(16) char smem[32768];   // As0,As1,Bs0,Bs1: 8KB each
  const int tid = threadIdx.x, wave = tid>>6, lane = tid&63;
  const int lr = lane&15, lg = lane>>4;
  const int m0 = blockIdx.x*128, n0 = blockIdx.y*128;
  const int wr = (wave>>1)*64, wc = (wave&1)*64;
  f32x4 acc[4][4] = {};
  const int srow = wave*32 + (lane>>2);   // staging row (+i*16)
  const int schk = lane&3;                // 16B chunk within 64B row

  auto stage = [&](int kt, int buf){
    char* Ab = smem + buf*8192;
    char* Bb = smem + 16384 + buf*8192;
    #pragma unroll
    for (int i = 0; i < 2; i++){
      int r = srow + i*16;
      async_copy16(A  + (size_t)(m0 + r)*K + kt + schk*8, Ab + (wave*32 + i*16)*64);
      async_copy16(Bt + (size_t)(n0 + r)*K + kt + schk*8, Bb + (wave*32 + i*16)*64);
    }
  };

  const int NT = K >> 5;
  stage(0, 0);
  for (int t = 0; t < NT; t++){
    const int c = t & 1;
    asm volatile("s_waitcnt vmcnt(0)" ::: "memory");
    __builtin_amdgcn_s_barrier();
    if (t+1 < NT) stage((t+1)<<5, c^1);

    const char* Ac = smem + c*8192;
    const char* Bc = smem + 16384 + c*8192;
    short8 a[4], b[4];
    #pragma unroll
    for (int mi = 0; mi < 4; mi++)
      a[mi] = *(const short8*)(Ac + (wr + mi*16 + lr)*64 + lg*16);
    #pragma unroll
    for (int ni = 0; ni < 4; ni++)
      b[ni] = *(const short8*)(Bc + (wc + ni*16 + lr)*64 + lg*16);
    #pragma unroll
    for (int mi = 0; mi < 4; mi++)
      #pragma unroll
      for (int ni = 0; ni < 4; ni++)
        acc[mi][ni] = __builtin_amdgcn_mfma_f32_16x16x32_bf16(a[mi], b[ni], acc[mi][ni], 0, 0, 0);
    asm volatile("s_waitcnt lgkmcnt(0)" ::: "memory");
    __builtin_amdgcn_sched_barrier(0);
    __builtin_amdgcn_s_barrier();
  }

  // epilogue: C row = (lane>>4)*4 + j, col = lane&15  [verified C/D layout]
  #pragma unroll
  for (int mi = 0; mi < 4; mi++)
  #pragma unroll
  for (int ni = 0; ni < 4; ni++)
  #pragma unroll
  for (int j = 0; j < 4; j++){
    int m = m0 + wr + mi*16 + lg*4 + j;
    int n = n0 + wc + ni*16 + lr;
    float v = acc[mi][ni][j] + bias[n];
    if (EPI == 0){
      outf[(size_t)m*N + n] = v;
    } else {
      int b_ = m >> 11, s = m & 2047;
      int t  = (n >= 1536) ? 2 : (n >= 768 ? 1 : 0);
      int hn = n - t*768;
      int h = hn >> 6, d = hn & 63;
      size_t base = (size_t)(b_*NH + h);
      if (t == 0)      oq [(base*SEQ + s)*HD + d] = f2bf(v * 0.1803368801f); // fold 0.125*log2e into Q
      else if (t == 1) ok [(base*SEQ + s)*HD + d] = f2bf(v);
      else             ovt[(base*HD + d)*SEQ + s] = f2bf(v);   // V stored transposed
    }
  }
}

// ---------------- flash attention: shared-KV LDS, swapped-operand ----------------
// 768 blocks x 128 threads (2 waves x 32 q-rows = 64-row tile). Pair (p,31-p)
// -> uniform 33 KV64-steps/block; 3 blocks/CU resident (LDS 42KB).
// K/V staged via global_load_lds double buffer, single-barrier counted pattern.
// Swapped QK (S^T = K*Q^T): per-lane scalar softmax state (2 q-rows/lane).
// This round: defer-max (local vote, THR=8 in log2 domain), per-lane partial
// lsum (row-reduce moved to epilogue), s_setprio around MFMA clusters,
// removed redundant per-step tail lgkm drain.
__launch_bounds__(128, 2)
__global__ void attn_kernel(const u16* __restrict__ q, const u16* __restrict__ k,
                            const u16* __restrict__ vt, u16* __restrict__ aout)
{
  __shared__ alignas(16) char smem[43008];
  // buf b: K at b*16384, V at b*16384+8192 (rows 128B, col-swizzled)
  // P bounce at 32768 + wave*5120 + h*2560  (64 rows x 40B)

  const int b1 = blockIdx.x;                 // 0..767
  const int xcd = b1 & 7, grp = b1 >> 3;     // grp 0..95
  const int bh = xcd*6 + (grp >> 4);         // 6 heads per XCD (L2 locality)
  const int pairblk = grp & 15;              // pair 0..15
  const int tid = threadIdx.x, wave = tid>>6, lane = tid&63;
  const int lr = lane&15, lg = lane>>4;
  const int b_ = bh / NH, h_ = bh % NH;
  const u16* qp = q  + (size_t)bh*SEQ*HD;
  const u16* kp = k  + (size_t)bh*SEQ*HD;
  const u16* vp = vt + (size_t)bh*HD*SEQ;
  char* Pw = smem + 32768 + wave*5120;
  const int fswz = (lr&7)<<4;
  const int c8s = (lane&7) ^ (lane>>3);      // staging source col swizzle

  auto stageKV = [&](int kv0, int buf){
    char* Kb = smem + buf*16384;
    char* Vb = Kb + 8192;
    #pragma unroll
    for (int r = 0; r < 4; r++){
      int row = r*16 + wave*8 + (lane>>3);
      async_copy16(kp + (size_t)(kv0 + row)*HD + c8s*8, Kb + r*2048 + wave*1024);
      async_copy16(vp + (size_t)row*SEQ + kv0 + c8s*8,  Vb + r*2048 + wave*1024);
    }
  };

  #pragma unroll 1
  for (int half = 0; half < 2; half++){
    const int t = half ? (31 - pairblk) : pairblk;   // 64-row tile 0..31
    const int nkv = t + 1;
    const int q0w = t*64 + wave*32;

    // Q^T B-frags: lane holds Q[q = q0w+h*16+lr][d = ks*32+lg*8+e]
    short8 bq[2][2];
    #pragma unroll
    for (int h = 0; h < 2; h++)
      #pragma unroll
      for (int ks = 0; ks < 2; ks++)
        bq[h][ks] = *(const short8*)(qp + (size_t)(q0w + h*16 + lr)*HD + ks*32 + lg*8);

    float mrow[2] = {-INFINITY, -INFINITY};
    float lsum[2] = {0.f, 0.f};   // per-lane PARTIAL row sum (reduced in epilogue)
    f32x4 o[4][2] = {};   // O^T: d = ni*16+lg*4+jj, q = h*16+lr

    // sync before overwriting buf0 (prev half readers), then prologue stage
    asm volatile("s_waitcnt vmcnt(0) lgkmcnt(0)" ::: "memory");
    __builtin_amdgcn_sched_barrier(0);
    __builtin_amdgcn_s_barrier();
    stageKV(0, 0);

    #pragma unroll 1
    for (int kvb = 0; kvb < nkv; kvb++){
      const int c = kvb & 1;
      const int kv0 = kvb*64;
      // my stage(kvb) + my prior LDS reads complete -> barrier -> all staged
      asm volatile("s_waitcnt vmcnt(0) lgkmcnt(0)" ::: "memory");
      __builtin_amdgcn_sched_barrier(0);
      __builtin_amdgcn_s_barrier();
      if (kvb+1 < nkv) stageKV(kv0 + 64, c^1);

      const char* Kb = smem + c*16384;
      const char* Vb = Kb + 8192;

      // ---- S^T = K Q^T : lane holds s[ni][h][jj] = S[q=h*16+lr][kv0+ni*16+lg*4+jj]
      f32x4 s[4][2] = {};
      __builtin_amdgcn_s_setprio(1);
      #pragma unroll
      for (int ni = 0; ni < 4; ni++){
        short8 k0 = *(const short8*)(Kb + (ni*16+lr)*128 + ((lg*16) ^ fswz));
        short8 k1 = *(const short8*)(Kb + (ni*16+lr)*128 + ((64 + lg*16) ^ fswz));
        #pragma unroll
        for (int h = 0; h < 2; h++){
          s[ni][h] = __builtin_amdgcn_mfma_f32_16x16x32_bf16(k0, bq[h][0], s[ni][h], 0,0,0);
          s[ni][h] = __builtin_amdgcn_mfma_f32_16x16x32_bf16(k1, bq[h][1], s[ni][h], 0,0,0);
        }
      }
      __builtin_amdgcn_s_setprio(0);

      // ---- causal mask (diagonal step only; Q pre-scaled by 0.125*log2e) ----
      if (kvb == nkv-1){
        #pragma unroll
        for (int ni = 0; ni < 4; ni++)
          #pragma unroll
          for (int h = 0; h < 2; h++)
            #pragma unroll
            for (int jj = 0; jj < 4; jj++){
              int col = kv0 + ni*16 + lg*4 + jj;
              int qrow = q0w + h*16 + lr;
              if (col > qrow) s[ni][h][jj] = -1e30f;
            }
      }

      // ---- online softmax: defer-max + per-lane partial lsum ----
      #pragma unroll
      for (int h = 0; h < 2; h++){
        float v0 = fmaxf(fmaxf(s[0][h][0], s[0][h][1]), fmaxf(s[0][h][2], s[0][h][3]));
        float v1 = fmaxf(fmaxf(s[1][h][0], s[1][h][1]), fmaxf(s[1][h][2], s[1][h][3]));
        float v2 = fmaxf(fmaxf(s[2][h][0], s[2][h][1]), fmaxf(s[2][h][2], s[2][h][3]));
        float v3 = fmaxf(fmaxf(s[3][h][0], s[3][h][1]), fmaxf(s[3][h][2], s[3][h][3]));
        float vloc = fmaxf(fmaxf(v0, v1), fmaxf(v2, v3));
        // local vote: if no lane's local max exceeds m+8, keep old max (P <= 2^8)
        if (!__all(vloc - mrow[h] <= 8.0f)){
          float v = fmaxf(vloc, __shfl_xor(vloc, 16));
          v = fmaxf(v, __shfl_xor(v, 32));
          float mn = fmaxf(mrow[h], v);
          float alpha = __builtin_amdgcn_exp2f(mrow[h] - mn);
          mrow[h] = mn;
          lsum[h] *= alpha;   // alpha row-uniform -> scaling partials is exact
          #pragma unroll
          for (int ni = 0; ni < 4; ni++)
            #pragma unroll
            for (int jj = 0; jj < 4; jj++)
              o[ni][h][jj] *= alpha;
        }
        const float mn = mrow[h];
        char* hb = Pw + h*2560;
        float psum = 0.f;
        #pragma unroll
        for (int ni = 0; ni < 4; ni++){
          float p0 = __builtin_amdgcn_exp2f(s[ni][h][0] - mn);
          float p1 = __builtin_amdgcn_exp2f(s[ni][h][1] - mn);
          float p2 = __builtin_amdgcn_exp2f(s[ni][h][2] - mn);
          float p3 = __builtin_amdgcn_exp2f(s[ni][h][3] - mn);
          psum += (p0+p1) + (p2+p3);
          int tl = lr + 16*(((ni&1)<<1) | (lg>>1));
          int wb = ((ni>>1)<<2) | ((lg&1)<<1);
          *(u32*)(hb + tl*40 + wb*4)     = pack_bf2(p0, p1);
          *(u32*)(hb + tl*40 + wb*4 + 4) = pack_bf2(p2, p3);
        }
        lsum[h] += psum;   // lane-local partial; no shuffles in the loop
      }

      // ---- read P^T B-frags (addr = lane*40 + ks*16, contiguous) ----
      union { u32 w[4]; short8 v; } pb[2][2];
      #pragma unroll
      for (int h = 0; h < 2; h++)
        #pragma unroll
        for (int ks = 0; ks < 2; ks++){
          const char* hb = Pw + h*2560 + (size_t)lane*40 + ks*16;
          pb[h][ks].w[0] = *(const u32*)(hb);
          pb[h][ks].w[1] = *(const u32*)(hb + 4);
          pb[h][ks].w[2] = *(const u32*)(hb + 8);
          pb[h][ks].w[3] = *(const u32*)(hb + 12);
        }

      // ---- O^T += V^T P^T ----
      __builtin_amdgcn_s_setprio(1);
      #pragma unroll
      for (int ni = 0; ni < 4; ni++){
        short8 v0 = *(const short8*)(Vb + (ni*16+lr)*128 + ((lg*16) ^ fswz));
        short8 v1 = *(const short8*)(Vb + (ni*16+lr)*128 + ((64 + lg*16) ^ fswz));
        #pragma unroll
        for (int h = 0; h < 2; h++){
          o[ni][h] = __builtin_amdgcn_mfma_f32_16x16x32_bf16(v0, pb[h][0].v, o[ni][h], 0,0,0);
          o[ni][h] = __builtin_amdgcn_mfma_f32_16x16x32_bf16(v1, pb[h][1].v, o[ni][h], 0,0,0);
        }
      }
      __builtin_amdgcn_s_setprio(0);
      // (no tail drain: top-of-loop vmcnt/lgkm drain + barrier covers buffer WAR;
      //  P-buffer WAR is wave-local and DS ops retire in order per wave)
    }

    // epilogue: reduce lsum partials (2 hops), lane writes its two q-rows
    #pragma unroll
    for (int h = 0; h < 2; h++){
      float ls = lsum[h];
      ls += __shfl_xor(ls, 16);
      ls += __shfl_xor(ls, 32);
      float inv = 1.0f / ls;
      u16* orow = aout + ((size_t)b_*SEQ + q0w + h*16 + lr)*D_MODEL + h_*HD;
      #pragma unroll
      for (int ni = 0; ni < 4; ni++){
        ushort4 w;
        w.x = f2bf(o[ni][h][0]*inv);
        w.y = f2bf(o[ni][h][1]*inv);
        w.z = f2bf(o[ni][h][2]*inv);
        w.w = f2bf(o[ni][h][3]*inv);
        *(ushort4*)(orow + ni*16 + lg*4) = w;
      }
    }
  }
}

extern "C" void kernel_launch(void* const* d_in, const int* in_sizes, int n_in,
                              void* d_out, int out_size, void* d_ws, size_t ws_size,
                              hipStream_t stream)
{
  const float* x    = (const float*)d_in[0];
  const float* Wqkv = (const float*)d_in[1];
  const float* bqkv = (const float*)d_in[2];
  const float* Wout = (const float*)d_in[3];
  const float* bout = (const float*)d_in[4];
  float* out = (float*)d_out;
  char* ws = (char*)d_ws;

  // workspace layout (bytes)
  u16* x_bf   = (u16*)(ws + 0);          // 8192x768   bf16 = 12,582,912
  u16* wqkv_t = (u16*)(ws + 12582912);   // 2304x768   bf16 =  3,538,944
  u16* wout_t = (u16*)(ws + 16121856);   //  768x768   bf16 =  1,179,648
  u16* qb     = (u16*)(ws + 17301504);   // [48][2048][64]  = 12,582,912
  u16* kb     = (u16*)(ws + 29884416);   // [48][2048][64]  = 12,582,912
  u16* vtb    = (u16*)(ws + 42467328);   // [48][64][2048]  = 12,582,912
  u16* attnb  = (u16*)(ws + 55050240);   // 8192x768   bf16 = 12,582,912

  cast4_kernel<<<6144, 256, 0, stream>>>(x, x_bf, (BATCH*SEQ*D_MODEL)/4);
  transpose_cast_kernel<<<dim3(12, 36), 256, 0, stream>>>(Wqkv, wqkv_t, 768, 2304);
  transpose_cast_kernel<<<dim3(12, 12), 256, 0, stream>>>(Wout, wout_t, 768, 768);

  gemm_bf16<1><<<dim3(64, 18), 256, 0, stream>>>(x_bf, wqkv_t, bqkv, nullptr,
                                                 qb, kb, vtb, MROWS, 3*D_MODEL, D_MODEL);

  attn_kernel<<<768, 128, 0, stream>>>(qb, kb, vtb, attnb);

  gemm_bf16<0><<<dim3(64, 6), 256, 0, stream>>>(attnb, wout_t, bout, out,
                                                nullptr, nullptr, nullptr, MROWS, D_MODEL, D_MODEL);
}

// Round 8
// 138.786 us; speedup vs baseline: 1.9188x; 1.0862x over previous
//
#include <hip/hip_runtime.h>
#include <hip/hip_bf16.h>

// Problem constants
#define D_MODEL 768
#define NH 12
#define HD 64
#define BATCH 4
#define SEQ 2048
#define BHN (BATCH*NH)        // 48
#define MROWS (BATCH*SEQ)     // 8192

typedef unsigned short u16;
typedef unsigned int u32;
typedef __attribute__((ext_vector_type(8))) short short8;
typedef __attribute__((ext_vector_type(4))) float f32x4;

__device__ inline u16 f2bf(float f){
  union { __hip_bfloat16 h; u16 u; } cv; cv.h = __float2bfloat16(f); return cv.u;
}
__device__ inline u32 pack_bf2(float a, float b){
  return (u32)f2bf(a) | ((u32)f2bf(b) << 16);
}

// async global->LDS, 16B per lane. LDS dest = wave-uniform base + lane*16.
__device__ inline void async_copy16(const void* g, void* l){
  __builtin_amdgcn_global_load_lds(
      (const __attribute__((address_space(1))) void*)g,
      (__attribute__((address_space(3))) void*)l, 16, 0, 0);
}

// ---------------- cast fp32 -> bf16, vectorized x4 ----------------
__global__ void cast4_kernel(const float* __restrict__ in, u16* __restrict__ out, int n4){
  int i = blockIdx.x*blockDim.x + threadIdx.x;
  if (i < n4){
    const float4 v = ((const float4*)in)[i];
    ushort4 o;
    o.x = f2bf(v.x); o.y = f2bf(v.y); o.z = f2bf(v.z); o.w = f2bf(v.w);
    ((ushort4*)out)[i] = o;
  }
}

// ---------------- transpose + cast: W[K][N] fp32 -> Wt[N][K] bf16 ----------------
__global__ void transpose_cast_kernel(const float* __restrict__ w, u16* __restrict__ wt,
                                      int K, int N){
  __shared__ u16 tile[64][65];
  int k0 = blockIdx.x*64, n0 = blockIdx.y*64;
  int c = threadIdx.x & 63, r0 = threadIdx.x >> 6;
  #pragma unroll
  for (int r = r0; r < 64; r += 4)
    tile[c][r] = f2bf(w[(size_t)(k0+r)*N + n0 + c]);
  __syncthreads();
  #pragma unroll
  for (int r = r0; r < 64; r += 4)
    wt[(size_t)(n0+r)*K + k0 + c] = tile[r][c];
}

// ---------------- bf16 GEMM: C[M,N] = A[M,K] @ Bt[N,K]^T ----------------
// 128x128 tile, BK=32, double-buffered LDS, ONE barrier per K-step.
// Safe: frag ds_reads are consumed by MFMAs before the barrier, so they are
// complete when any wave's stage after the NEXT barrier overwrites that buffer.
template<int EPI>
__launch_bounds__(256)
__global__ void gemm_bf16(const u16* __restrict__ A, const u16* __restrict__ Bt,
                          const float* __restrict__ bias, float* __restrict__ outf,
                          u16* __restrict__ oq, u16* __restrict__ ok, u16* __restrict__ ovt,
                          int M, int N, int K)
{
  __shared__ alignas(16) char smem[32768];   // As0,As1,Bs0,Bs1: 8KB each
  const int tid = threadIdx.x, wave = tid>>6, lane = tid&63;
  const int lr = lane&15, lg = lane>>4;
  const int m0 = blockIdx.x*128, n0 = blockIdx.y*128;
  const int wr = (wave>>1)*64, wc = (wave&1)*64;
  f32x4 acc[4][4] = {};
  const int srow = wave*32 + (lane>>2);   // staging row (+i*16)
  const int schk = lane&3;                // 16B chunk within 64B row

  auto stage = [&](int kt, int buf){
    char* Ab = smem + buf*8192;
    char* Bb = smem + 16384 + buf*8192;
    #pragma unroll
    for (int i = 0; i < 2; i++){
      int r = srow + i*16;
      async_copy16(A  + (size_t)(m0 + r)*K + kt + schk*8, Ab + (wave*32 + i*16)*64);
      async_copy16(Bt + (size_t)(n0 + r)*K + kt + schk*8, Bb + (wave*32 + i*16)*64);
    }
  };

  const int NT = K >> 5;
  stage(0, 0);
  for (int t = 0; t < NT; t++){
    const int c = t & 1;
    asm volatile("s_waitcnt vmcnt(0)" ::: "memory");
    __builtin_amdgcn_s_barrier();
    if (t+1 < NT) stage((t+1)<<5, c^1);

    const char* Ac = smem + c*8192;
    const char* Bc = smem + 16384 + c*8192;
    short8 a[4], b[4];
    #pragma unroll
    for (int mi = 0; mi < 4; mi++)
      a[mi] = *(const short8*)(Ac + (wr + mi*16 + lr)*64 + lg*16);
    #pragma unroll
    for (int ni = 0; ni < 4; ni++)
      b[ni] = *(const short8*)(Bc + (wc + ni*16 + lr)*64 + lg*16);
    #pragma unroll
    for (int mi = 0; mi < 4; mi++)
      #pragma unroll
      for (int ni = 0; ni < 4; ni++)
        acc[mi][ni] = __builtin_amdgcn_mfma_f32_16x16x32_bf16(a[mi], b[ni], acc[mi][ni], 0, 0, 0);
  }

  // epilogue: C row = (lane>>4)*4 + j, col = lane&15  [verified C/D layout]
  #pragma unroll
  for (int mi = 0; mi < 4; mi++)
  #pragma unroll
  for (int ni = 0; ni < 4; ni++)
  #pragma unroll
  for (int j = 0; j < 4; j++){
    int m = m0 + wr + mi*16 + lg*4 + j;
    int n = n0 + wc + ni*16 + lr;
    float v = acc[mi][ni][j] + bias[n];
    if (EPI == 0){
      outf[(size_t)m*N + n] = v;
    } else {
      int b_ = m >> 11, s = m & 2047;
      int t  = (n >= 1536) ? 2 : (n >= 768 ? 1 : 0);
      int hn = n - t*768;
      int h = hn >> 6, d = hn & 63;
      size_t base = (size_t)(b_*NH + h);
      if (t == 0)      oq [(base*SEQ + s)*HD + d] = f2bf(v * 0.1803368801f); // fold 0.125*log2e into Q
      else if (t == 1) ok [(base*SEQ + s)*HD + d] = f2bf(v);
      else             ovt[(base*HD + d)*SEQ + s] = f2bf(v);   // V stored transposed
    }
  }
}

// ---------------- flash attention: merged causal pair-sweep ----------------
// 768 blocks x 256 threads (4 waves x 32 q-rows). Block owns tile pair
// (p, 31-p) of 64-row tiles and sweeps KV ONCE over 32-p steps: the hi tile
// (h=0) is active all steps, the lo tile (h=1) only while kvb <= p. Work per
// block ~uniform (17-19 full-chain units). 3 blocks/CU (LDS 52KB) -> 12
// waves/CU to interleave the per-wave chains. Single barrier per step.
// Swapped QK (S^T = K*Q^T), per-lane scalar softmax, defer-max, partial lsum.
__launch_bounds__(256, 3)
__global__ void attn_kernel(const u16* __restrict__ q, const u16* __restrict__ k,
                            const u16* __restrict__ vt, u16* __restrict__ aout)
{
  __shared__ alignas(16) char smem[53248];
  // KV dbuf: buf b at b*16384 (K 8KB + V 8KB), rows 128B, col-swizzled
  // P bounce at 32768 + wave*5120 + h*2560  (rows of 40B)

  const int b1 = blockIdx.x;                 // 0..767
  const int xcd = b1 & 7, grp = b1 >> 3;     // grp 0..95
  const int bh = xcd*6 + (grp >> 4);         // 6 heads per XCD (L2 locality)
  const int p  = grp & 15;                   // lo tile index 0..15
  const int hi = 31 - p;                     // hi tile index 16..31
  const int tid = threadIdx.x, wave = tid>>6, lane = tid&63;
  const int lr = lane&15, lg = lane>>4;
  const int b_ = bh / NH, h_ = bh % NH;
  const u16* qp = q  + (size_t)bh*SEQ*HD;
  const u16* kp = k  + (size_t)bh*SEQ*HD;
  const u16* vp = vt + (size_t)bh*HD*SEQ;
  char* Pw = smem + 32768 + wave*5120;
  const int fswz = (lr&7)<<4;
  const int c8s = (lane&7) ^ (lane>>3);      // staging source col swizzle
  const int nkv = hi + 1;                    // total KV64 steps

  auto stageKV = [&](int kv0, int buf){
    char* Kb = smem + buf*16384;
    char* Vb = Kb + 8192;
    #pragma unroll
    for (int r = 0; r < 2; r++){
      int row = wave*16 + r*8 + (lane>>3);
      async_copy16(kp + (size_t)(kv0 + row)*HD + c8s*8, Kb + (wave*16 + r*8)*128);
      async_copy16(vp + (size_t)row*SEQ + kv0 + c8s*8,  Vb + (wave*16 + r*8)*128);
    }
  };

  const int qrow[2] = { hi*64 + wave*16 + lr, p*64 + wave*16 + lr };

  // Q^T B-frags: lane holds Q[qrow[h]][d = ks*32+lg*8+e]
  short8 bq[2][2];
  #pragma unroll
  for (int h = 0; h < 2; h++)
    #pragma unroll
    for (int ks = 0; ks < 2; ks++)
      bq[h][ks] = *(const short8*)(qp + (size_t)qrow[h]*HD + ks*32 + lg*8);

  float mrow[2] = {-INFINITY, -INFINITY};
  float lsum[2] = {0.f, 0.f};   // per-lane PARTIAL row sums (reduced in epilogue)
  f32x4 o[4][2] = {};           // O^T: d = ni*16+lg*4+jj, q = qrow[h]

  stageKV(0, 0);

  // per-h softmax + P-pack (shared by both phases)
  auto softmax_pack = [&](f32x4 (&s)[4][2], int h, bool domask, int kv0, int qr){
    if (domask){
      #pragma unroll
      for (int ni = 0; ni < 4; ni++)
        #pragma unroll
        for (int jj = 0; jj < 4; jj++){
          int col = kv0 + ni*16 + lg*4 + jj;
          if (col > qr) s[ni][h][jj] = -1e30f;
        }
    }
    float v0 = fmaxf(fmaxf(s[0][h][0], s[0][h][1]), fmaxf(s[0][h][2], s[0][h][3]));
    float v1 = fmaxf(fmaxf(s[1][h][0], s[1][h][1]), fmaxf(s[1][h][2], s[1][h][3]));
    float v2 = fmaxf(fmaxf(s[2][h][0], s[2][h][1]), fmaxf(s[2][h][2], s[2][h][3]));
    float v3 = fmaxf(fmaxf(s[3][h][0], s[3][h][1]), fmaxf(s[3][h][2], s[3][h][3]));
    float vloc = fmaxf(fmaxf(v0, v1), fmaxf(v2, v3));
    // local vote: if no lane's local max exceeds m+8, keep old max (P <= 2^8)
    if (!__all(vloc - mrow[h] <= 8.0f)){
      float v = fmaxf(vloc, __shfl_xor(vloc, 16));
      v = fmaxf(v, __shfl_xor(v, 32));
      float mn = fmaxf(mrow[h], v);
      float alpha = __builtin_amdgcn_exp2f(mrow[h] - mn);
      mrow[h] = mn;
      lsum[h] *= alpha;   // alpha row-uniform -> scaling partials is exact
      #pragma unroll
      for (int ni = 0; ni < 4; ni++)
        #pragma unroll
        for (int jj = 0; jj < 4; jj++)
          o[ni][h][jj] *= alpha;
    }
    const float mn = mrow[h];
    char* hb = Pw + h*2560;
    float psum = 0.f;
    #pragma unroll
    for (int ni = 0; ni < 4; ni++){
      float p0 = __builtin_amdgcn_exp2f(s[ni][h][0] - mn);
      float p1 = __builtin_amdgcn_exp2f(s[ni][h][1] - mn);
      float p2 = __builtin_amdgcn_exp2f(s[ni][h][2] - mn);
      float p3 = __builtin_amdgcn_exp2f(s[ni][h][3] - mn);
      psum += (p0+p1) + (p2+p3);
      int tl = lr + 16*(((ni&1)<<1) | (lg>>1));
      int wb = ((ni>>1)<<2) | ((lg&1)<<1);
      *(u32*)(hb + tl*40 + wb*4)     = pack_bf2(p0, p1);
      *(u32*)(hb + tl*40 + wb*4 + 4) = pack_bf2(p2, p3);
    }
    lsum[h] += psum;
  };

  auto read_pb = [&](int h, short8& r0, short8& r1){
    const char* hb = Pw + h*2560 + (size_t)lane*40;
    union { u32 w[4]; short8 v; } a, b;
    a.w[0] = *(const u32*)(hb);      a.w[1] = *(const u32*)(hb + 4);
    a.w[2] = *(const u32*)(hb + 8);  a.w[3] = *(const u32*)(hb + 12);
    b.w[0] = *(const u32*)(hb + 16); b.w[1] = *(const u32*)(hb + 20);
    b.w[2] = *(const u32*)(hb + 24); b.w[3] = *(const u32*)(hb + 28);
    r0 = a.v; r1 = b.v;
  };

  int kvb = 0;

  // ---------- phase 1: both tiles active (kvb = 0..p) ----------
  #pragma unroll 1
  for (; kvb <= p; kvb++){
    const int c = kvb & 1;
    const int kv0 = kvb*64;
    asm volatile("s_waitcnt vmcnt(0)" ::: "memory");
    __builtin_amdgcn_s_barrier();
    if (kvb+1 < nkv) stageKV(kv0 + 64, c^1);

    const char* Kb = smem + c*16384;
    const char* Vb = Kb + 8192;

    f32x4 s[4][2] = {};
    __builtin_amdgcn_s_setprio(1);
    #pragma unroll
    for (int ni = 0; ni < 4; ni++){
      short8 k0 = *(const short8*)(Kb + (ni*16+lr)*128 + ((lg*16) ^ fswz));
      short8 k1 = *(const short8*)(Kb + (ni*16+lr)*128 + ((64 + lg*16) ^ fswz));
      #pragma unroll
      for (int h = 0; h < 2; h++){
        s[ni][h] = __builtin_amdgcn_mfma_f32_16x16x32_bf16(k0, bq[h][0], s[ni][h], 0,0,0);
        s[ni][h] = __builtin_amdgcn_mfma_f32_16x16x32_bf16(k1, bq[h][1], s[ni][h], 0,0,0);
      }
    }
    __builtin_amdgcn_s_setprio(0);

    softmax_pack(s, 0, false, kv0, qrow[0]);          // hi tile: never masked here
    softmax_pack(s, 1, kvb == p, kv0, qrow[1]);       // lo tile: diagonal at kvb==p

    short8 pb[2][2];
    read_pb(0, pb[0][0], pb[0][1]);
    read_pb(1, pb[1][0], pb[1][1]);

    __builtin_amdgcn_s_setprio(1);
    #pragma unroll
    for (int ni = 0; ni < 4; ni++){
      short8 v0 = *(const short8*)(Vb + (ni*16+lr)*128 + ((lg*16) ^ fswz));
      short8 v1 = *(const short8*)(Vb + (ni*16+lr)*128 + ((64 + lg*16) ^ fswz));
      #pragma unroll
      for (int h = 0; h < 2; h++){
        o[ni][h] = __builtin_amdgcn_mfma_f32_16x16x32_bf16(v0, pb[h][0], o[ni][h], 0,0,0);
        o[ni][h] = __builtin_amdgcn_mfma_f32_16x16x32_bf16(v1, pb[h][1], o[ni][h], 0,0,0);
      }
    }
    __builtin_amdgcn_s_setprio(0);
  }

  // ---------- phase 2: hi tile only (kvb = p+1..hi) ----------
  #pragma unroll 1
  for (; kvb < nkv; kvb++){
    const int c = kvb & 1;
    const int kv0 = kvb*64;
    asm volatile("s_waitcnt vmcnt(0)" ::: "memory");
    __builtin_amdgcn_s_barrier();
    if (kvb+1 < nkv) stageKV(kv0 + 64, c^1);

    const char* Kb = smem + c*16384;
    const char* Vb = Kb + 8192;

    f32x4 s[4][2];
    #pragma unroll
    for (int ni = 0; ni < 4; ni++) s[ni][0] = (f32x4){0.f,0.f,0.f,0.f};
    __builtin_amdgcn_s_setprio(1);
    #pragma unroll
    for (int ni = 0; ni < 4; ni++){
      short8 k0 = *(const short8*)(Kb + (ni*16+lr)*128 + ((lg*16) ^ fswz));
      short8 k1 = *(const short8*)(Kb + (ni*16+lr)*128 + ((64 + lg*16) ^ fswz));
      s[ni][0] = __builtin_amdgcn_mfma_f32_16x16x32_bf16(k0, bq[0][0], s[ni][0], 0,0,0);
      s[ni][0] = __builtin_amdgcn_mfma_f32_16x16x32_bf16(k1, bq[0][1], s[ni][0], 0,0,0);
    }
    __builtin_amdgcn_s_setprio(0);

    softmax_pack(s, 0, kvb == hi, kv0, qrow[0]);      // hi tile diagonal at last step

    short8 pb0, pb1;
    read_pb(0, pb0, pb1);

    __builtin_amdgcn_s_setprio(1);
    #pragma unroll
    for (int ni = 0; ni < 4; ni++){
      short8 v0 = *(const short8*)(Vb + (ni*16+lr)*128 + ((lg*16) ^ fswz));
      short8 v1 = *(const short8*)(Vb + (ni*16+lr)*128 + ((64 + lg*16) ^ fswz));
      o[ni][0] = __builtin_amdgcn_mfma_f32_16x16x32_bf16(v0, pb0, o[ni][0], 0,0,0);
      o[ni][0] = __builtin_amdgcn_mfma_f32_16x16x32_bf16(v1, pb1, o[ni][0], 0,0,0);
    }
    __builtin_amdgcn_s_setprio(0);
  }

  // epilogue: reduce lsum partials (2 hops), lane writes its two q-rows
  #pragma unroll
  for (int h = 0; h < 2; h++){
    float ls = lsum[h];
    ls += __shfl_xor(ls, 16);
    ls += __shfl_xor(ls, 32);
    float inv = 1.0f / ls;
    u16* orow = aout + ((size_t)b_*SEQ + qrow[h])*D_MODEL + h_*HD;
    #pragma unroll
    for (int ni = 0; ni < 4; ni++){
      ushort4 w;
      w.x = f2bf(o[ni][h][0]*inv);
      w.y = f2bf(o[ni][h][1]*inv);
      w.z = f2bf(o[ni][h][2]*inv);
      w.w = f2bf(o[ni][h][3]*inv);
      *(ushort4*)(orow + ni*16 + lg*4) = w;
    }
  }
}

extern "C" void kernel_launch(void* const* d_in, const int* in_sizes, int n_in,
                              void* d_out, int out_size, void* d_ws, size_t ws_size,
                              hipStream_t stream)
{
  const float* x    = (const float*)d_in[0];
  const float* Wqkv = (const float*)d_in[1];
  const float* bqkv = (const float*)d_in[2];
  const float* Wout = (const float*)d_in[3];
  const float* bout = (const float*)d_in[4];
  float* out = (float*)d_out;
  char* ws = (char*)d_ws;

  // workspace layout (bytes)
  u16* x_bf   = (u16*)(ws + 0);          // 8192x768   bf16 = 12,582,912
  u16* wqkv_t = (u16*)(ws + 12582912);   // 2304x768   bf16 =  3,538,944
  u16* wout_t = (u16*)(ws + 16121856);   //  768x768   bf16 =  1,179,648
  u16* qb     = (u16*)(ws + 17301504);   // [48][2048][64]  = 12,582,912
  u16* kb     = (u16*)(ws + 29884416);   // [48][2048][64]  = 12,582,912
  u16* vtb    = (u16*)(ws + 42467328);   // [48][64][2048]  = 12,582,912
  u16* attnb  = (u16*)(ws + 55050240);   // 8192x768   bf16 = 12,582,912

  cast4_kernel<<<6144, 256, 0, stream>>>(x, x_bf, (BATCH*SEQ*D_MODEL)/4);
  transpose_cast_kernel<<<dim3(12, 36), 256, 0, stream>>>(Wqkv, wqkv_t, 768, 2304);
  transpose_cast_kernel<<<dim3(12, 12), 256, 0, stream>>>(Wout, wout_t, 768, 768);

  gemm_bf16<1><<<dim3(64, 18), 256, 0, stream>>>(x_bf, wqkv_t, bqkv, nullptr,
                                                 qb, kb, vtb, MROWS, 3*D_MODEL, D_MODEL);

  attn_kernel<<<768, 256, 0, stream>>>(qb, kb, vtb, attnb);

  gemm_bf16<0><<<dim3(64, 6), 256, 0, stream>>>(attnb, wout_t, bout, out,
                                                nullptr, nullptr, nullptr, MROWS, D_MODEL, D_MODEL);
}